// Round 1
// baseline (187.879 us; speedup 1.0000x reference)
//
#include <hip/hip_runtime.h>

#define B_ 8
#define S_ 32
#define N_ 512
#define E_ 8192
#define T_ 31

typedef __attribute__((ext_vector_type(8))) __bf16 bf16x8;
typedef __attribute__((ext_vector_type(4))) float f32x4;
typedef unsigned short u16;
typedef unsigned int u32;

__device__ __forceinline__ u16 f2b(float f) {
    union { float f; u32 u; } v; v.f = f;
    u32 r = v.u + 0x7FFF + ((v.u >> 16) & 1);
    return (u16)(r >> 16);
}

__device__ __forceinline__ f32x4 mfma16(bf16x8 a, bf16x8 b, f32x4 c) {
    return __builtin_amdgcn_mfma_f32_16x16x32_bf16(a, b, c, 0, 0, 0);
}

// ---------------- adjacency build ----------------
__global__ void deg_k(const int* __restrict__ ei, const float* __restrict__ ew,
                      float* __restrict__ deg) {
    int e = blockIdx.x * 256 + threadIdx.x;
    if (e >= E_ + N_) return;
    int col; float w;
    if (e < E_) { col = ei[E_ + e]; w = ew[e]; }
    else        { col = e - E_;     w = 1.f;  }
    atomicAdd(deg + col, w);
}

__global__ void dis_k(float* __restrict__ deg, float* __restrict__ dis) {
    int n = blockIdx.x * 256 + threadIdx.x;
    if (n >= N_) return;
    float d = deg[n];
    dis[n] = (d > 0.f) ? rsqrtf(d) : 0.f;
}

// S[src*N + tgt] = A_hat[tgt, src]
__global__ void scat_k(const int* __restrict__ ei, const float* __restrict__ ew,
                       const float* __restrict__ dis, float* __restrict__ S) {
    int e = blockIdx.x * 256 + threadIdx.x;
    if (e >= E_ + N_) return;
    int row, col; float w;
    if (e < E_) { row = ei[e]; col = ei[E_ + e]; w = ew[e]; }
    else        { row = col = e - E_;            w = 1.f;  }
    atomicAdd(S + row * N_ + col, dis[row] * w * dis[col]);
}

// rs[m] = sum_n A_hat[m,n] = sum_n S[n*N+m]
__global__ void rs_k(const float* __restrict__ S, float* __restrict__ rs) {
    int m = blockIdx.x * 256 + threadIdx.x;
    if (m >= N_) return;
    float s = 0.f;
    for (int n = 0; n < N_; ++n) s += S[n * N_ + m];
    rs[m] = s;
}

// ---------------- coefficient collapse ----------------
__global__ void coef_k(const float* __restrict__ start_w, const float* __restrict__ start_b,
                       const float* __restrict__ filt_w, const float* __restrict__ filt_b,
                       const float* __restrict__ gate_w, const float* __restrict__ gate_b,
                       const float* __restrict__ gcn_w, float* __restrict__ coef) {
    __shared__ float sw[64], sb[64], A0[64], A1[64], C0[64];
    int o = threadIdx.x;
    sw[o] = start_w[o]; sb[o] = start_b[o];
    __syncthreads();
    float a0 = 0, a1 = 0, c = 0, g0 = 0, g1 = 0, gc = 0;
    for (int r = 0; r < 64; ++r) {
        float f0 = filt_w[(o * 64 + r) * 2], f1 = filt_w[(o * 64 + r) * 2 + 1];
        a0 += f0 * sw[r]; a1 += f1 * sw[r]; c += (f0 + f1) * sb[r];
        float q0 = gate_w[(o * 64 + r) * 2], q1 = gate_w[(o * 64 + r) * 2 + 1];
        g0 += q0 * sw[r]; g1 += q1 * sw[r]; gc += (q0 + q1) * sb[r];
    }
    c += filt_b[o]; gc += gate_b[o];
    A0[o] = a0; A1[o] = a1; C0[o] = c;
    __syncthreads();
    float u0 = 0, u1 = 0, u2 = 0;
    for (int d = 0; d < 64; ++d) {
        float g = gcn_w[o * 64 + d];
        u0 += g * A0[d]; u1 += g * A1[d]; u2 += g * C0[d];
    }
    coef[o] = u0; coef[64 + o] = u1; coef[128 + o] = u2;
    coef[192 + o] = g0; coef[256 + o] = g1; coef[320 + o] = gc;
}

// ---------------- weight conversion to swizzled bf16 ----------------
__global__ void wconv_k(const float* __restrict__ skip_w, const float* __restrict__ end1_w,
                        const float* __restrict__ end2_w,
                        u16* __restrict__ W1, u16* __restrict__ W2, u16* __restrict__ W3) {
    int i = blockIdx.x * 256 + threadIdx.x;
    if (i < 16384)  { int s = i >> 6,  o = i & 63;  W1[(s << 6) | (o ^ ((s & 7) << 3))] = f2b(skip_w[i]); }
    if (i < 131072) { int e = i >> 8,  s = i & 255; W2[(e << 8) | (s ^ ((e & 7) << 3))] = f2b(end1_w[i]); }
    if (i < 8192)   { int p = i >> 9,  e = i & 511;
                      float v = (p < 12) ? end2_w[i] : 0.f;
                      W3[(p << 9) | (e ^ ((p & 7) << 3))] = f2b(v); }
}

// ---------------- Y = X @ A_hat^T : Y[bt,m] = sum_n S[n*N+m]*x[bt,n] ----------------
__global__ void y_k(const float* __restrict__ x, const float* __restrict__ S,
                    float* __restrict__ Y) {
    __shared__ float xs[4][512];
    const int tid = threadIdx.x;
    const int m = blockIdx.x * 256 + tid;
    const int bt0 = blockIdx.y * 4;
#pragma unroll
    for (int i = 0; i < 8; ++i) {
        int idx = tid + i * 256;
        xs[idx >> 9][idx & 511] = x[(bt0 + (idx >> 9)) * 512 + (idx & 511)];
    }
    __syncthreads();
    float a0 = 0, a1 = 0, a2 = 0, a3 = 0;
#pragma unroll 4
    for (int n = 0; n < 512; ++n) {
        float sv = S[n * 512 + m];
        a0 += xs[0][n] * sv; a1 += xs[1][n] * sv;
        a2 += xs[2][n] * sv; a3 += xs[3][n] * sv;
    }
    Y[(bt0 + 0) * 512 + m] = a0; Y[(bt0 + 1) * 512 + m] = a1;
    Y[(bt0 + 2) * 512 + m] = a2; Y[(bt0 + 3) * 512 + m] = a3;
}

// ---------------- fused hg -> skip -> end1 -> end2 ----------------
__launch_bounds__(256, 1)
__global__ void fused_k(const float* __restrict__ x, const float* __restrict__ Y,
                        const float* __restrict__ rs, const float* __restrict__ coef,
                        const float* __restrict__ gcn_b, const float* __restrict__ skip_b,
                        const float* __restrict__ end1_b,
                        const u16* __restrict__ W1, const u16* __restrict__ W2,
                        const u16* __restrict__ W3, float* __restrict__ part) {
    __shared__ __align__(16) u16 HG[64 * 64];    // [pix][o]   swizzled
    __shared__ __align__(16) u16 SK[64 * 256];   // [pix][s]   swizzled
    __shared__ __align__(16) u16 E1[64 * 512];   // [pix][e]   swizzled
    __shared__ float xs0[64], xs1[64], ys0[64], ys1[64], rsl[64];
    __shared__ float cf[384], gb[64], bsk[256], be1[512];

    const int tid = threadIdx.x;
    const int wid = tid >> 6;
    const int lane = tid & 63;
    const int lr = lane & 15;
    const int lh = lane >> 4;

    const int bid = blockIdx.x;
    const int ntile = bid & 7;
    const int btix = bid >> 3;       // b*31 + t
    const int t = btix % 31;
    const int b = btix / 31;
    const int n0 = ntile * 64;
    const int bt = b * 32 + t;

    if (tid < 64) {
        xs0[tid] = x[bt * 512 + n0 + tid];
        xs1[tid] = x[(bt + 1) * 512 + n0 + tid];
        ys0[tid] = Y[bt * 512 + n0 + tid];
        ys1[tid] = Y[(bt + 1) * 512 + n0 + tid];
        rsl[tid] = rs[n0 + tid];
        gb[tid]  = gcn_b[tid];
    }
    cf[tid] = coef[tid];
    if (tid < 128) cf[256 + tid] = coef[256 + tid];
    bsk[tid] = skip_b[tid];
    be1[tid] = end1_b[tid];
    be1[tid + 256] = end1_b[tid + 256];
    __syncthreads();

    // phase A: hg = tanh(fg) * sigmoid(g)
#pragma unroll
    for (int k = 0; k < 16; ++k) {
        const int v = tid + k * 256;
        const int pix = v >> 6;
        const int o = v & 63;
        const float fgv = cf[o] * ys0[pix] + cf[64 + o] * ys1[pix]
                        + cf[128 + o] * rsl[pix] + gb[o];
        const float ggv = cf[192 + o] * xs0[pix] + cf[256 + o] * xs1[pix] + cf[320 + o];
        const float hv = tanhf(fgv) / (1.f + __expf(-ggv));
        HG[(pix << 6) | (o ^ ((pix & 7) << 3))] = f2b(hv);
    }
    __syncthreads();

    // GEMM1 (transposed): SKIP^T = skip_w x HG^T.  A=W1[s][o] (global), B=HG[pix][o] (LDS)
    {
        const int s0 = wid * 64;
        f32x4 acc[4][4];
#pragma unroll
        for (int i = 0; i < 4; ++i)
#pragma unroll
            for (int j = 0; j < 4; ++j) acc[i][j] = (f32x4){0.f, 0.f, 0.f, 0.f};
#pragma unroll
        for (int kk = 0; kk < 64; kk += 32) {
            const int kb = kk + lh * 8;
            bf16x8 a[4], bv[4];
#pragma unroll
            for (int i = 0; i < 4; ++i) {
                const int sr = s0 + i * 16 + lr;
                a[i] = *(const bf16x8*)(W1 + (sr << 6) + (kb ^ ((sr & 7) << 3)));
                const int pr = i * 16 + lr;
                bv[i] = *(const bf16x8*)(HG + (pr << 6) + (kb ^ ((pr & 7) << 3)));
            }
#pragma unroll
            for (int i = 0; i < 4; ++i)
#pragma unroll
                for (int j = 0; j < 4; ++j)
                    acc[i][j] = mfma16(a[i], bv[j], acc[i][j]);
        }
#pragma unroll
        for (int i = 0; i < 4; ++i) {
#pragma unroll
            for (int j = 0; j < 4; ++j) {
                const int pix = j * 16 + lr;
                const int xw = (pix & 7) << 3;
#pragma unroll
                for (int r = 0; r < 4; r += 2) {
                    const int s = s0 + i * 16 + lh * 4 + r;
                    const float v0 = fmaxf(acc[i][j][r] + bsk[s], 0.f);
                    const float v1 = fmaxf(acc[i][j][r + 1] + bsk[s + 1], 0.f);
                    *(u32*)(SK + (pix << 8) + (s ^ xw)) = (u32)f2b(v0) | ((u32)f2b(v1) << 16);
                }
            }
        }
    }
    __syncthreads();

    // GEMM2 (transposed): E1^T = end1_w x SKIP^T.  A=W2[e][s] (global), B=SK[pix][s] (LDS)
    {
        const int e0 = wid * 128;
        f32x4 acc[8][4];
#pragma unroll
        for (int i = 0; i < 8; ++i)
#pragma unroll
            for (int j = 0; j < 4; ++j) acc[i][j] = (f32x4){0.f, 0.f, 0.f, 0.f};
#pragma unroll
        for (int kk = 0; kk < 256; kk += 32) {
            const int kb = kk + lh * 8;
            bf16x8 a[8], bv[4];
#pragma unroll
            for (int i = 0; i < 8; ++i) {
                const int er = e0 + i * 16 + lr;
                a[i] = *(const bf16x8*)(W2 + (er << 8) + (kb ^ ((er & 7) << 3)));
            }
#pragma unroll
            for (int j = 0; j < 4; ++j) {
                const int pr = j * 16 + lr;
                bv[j] = *(const bf16x8*)(SK + (pr << 8) + (kb ^ ((pr & 7) << 3)));
            }
#pragma unroll
            for (int i = 0; i < 8; ++i)
#pragma unroll
                for (int j = 0; j < 4; ++j)
                    acc[i][j] = mfma16(a[i], bv[j], acc[i][j]);
        }
#pragma unroll
        for (int i = 0; i < 8; ++i) {
#pragma unroll
            for (int j = 0; j < 4; ++j) {
                const int pix = j * 16 + lr;
                const int xw = (pix & 7) << 3;
#pragma unroll
                for (int r = 0; r < 4; r += 2) {
                    const int e = e0 + i * 16 + lh * 4 + r;
                    const float v0 = fmaxf(acc[i][j][r] + be1[e], 0.f);
                    const float v1 = fmaxf(acc[i][j][r + 1] + be1[e + 1], 0.f);
                    *(u32*)(E1 + (pix << 9) + (e ^ xw)) = (u32)f2b(v0) | ((u32)f2b(v1) << 16);
                }
            }
        }
    }
    __syncthreads();

    // GEMM3 (transposed): OUT^T = end2_w x E1^T.  A=W3[p][e] (global), B=E1[pix][e] (LDS)
    {
        f32x4 acc0 = (f32x4){0.f, 0.f, 0.f, 0.f};
        f32x4 acc1 = (f32x4){0.f, 0.f, 0.f, 0.f};
        const int prow = wid * 16 + lr;          // pixel (column of output tile)
        const int xwp = (prow & 7) << 3;
        const int xw3 = (lr & 7) << 3;
#pragma unroll
        for (int kk = 0; kk < 512; kk += 64) {
            const int k0 = kk + lh * 8;
            const int k1 = kk + 32 + lh * 8;
            bf16x8 a0 = *(const bf16x8*)(W3 + (lr << 9) + (k0 ^ xw3));
            bf16x8 b0 = *(const bf16x8*)(E1 + (prow << 9) + (k0 ^ xwp));
            bf16x8 a1 = *(const bf16x8*)(W3 + (lr << 9) + (k1 ^ xw3));
            bf16x8 b1 = *(const bf16x8*)(E1 + (prow << 9) + (k1 ^ xwp));
            acc0 = mfma16(a0, b0, acc0);
            acc1 = mfma16(a1, b1, acc1);
        }
#pragma unroll
        for (int r = 0; r < 4; ++r) {
            const int pp = lh * 4 + r;
            if (pp < 12)
                part[(btix * 12 + pp) * 512 + n0 + prow] = acc0[r] + acc1[r];
        }
    }
}

// ---------------- mean over t + end2 bias ----------------
__global__ void reduce_k(const float* __restrict__ part, const float* __restrict__ end2_b,
                         float* __restrict__ out) {
    int i = blockIdx.x * 256 + threadIdx.x;
    if (i >= 8 * 12 * 512) return;
    int n = i & 511;
    int p = (i >> 9) % 12;
    int b = i / (12 * 512);
    const float* src = part + ((b * 31) * 12 + p) * 512 + n;
    float s = 0.f;
#pragma unroll
    for (int t = 0; t < 31; ++t) s += src[t * 12 * 512];
    out[i] = s * (1.f / 31.f) + end2_b[p];
}

extern "C" void kernel_launch(void* const* d_in, const int* in_sizes, int n_in,
                              void* d_out, int out_size, void* d_ws, size_t ws_size,
                              hipStream_t stream) {
    const float* x       = (const float*)d_in[0];
    const int*   ei      = (const int*)  d_in[1];
    const float* ew      = (const float*)d_in[2];
    const float* start_w = (const float*)d_in[3];
    const float* start_b = (const float*)d_in[4];
    const float* filt_w  = (const float*)d_in[5];
    const float* filt_b  = (const float*)d_in[6];
    const float* gate_w  = (const float*)d_in[7];
    const float* gate_b  = (const float*)d_in[8];
    const float* gcn_w   = (const float*)d_in[9];
    const float* gcn_b   = (const float*)d_in[10];
    const float* skip_w  = (const float*)d_in[13];
    const float* skip_b  = (const float*)d_in[14];
    const float* end1_w  = (const float*)d_in[15];
    const float* end1_b  = (const float*)d_in[16];
    const float* end2_w  = (const float*)d_in[17];
    const float* end2_b  = (const float*)d_in[18];
    float* out = (float*)d_out;

    char* ws = (char*)d_ws;
    float* S    = (float*)(ws);                 // 1,048,576 B
    float* deg  = (float*)(ws + 1048576);       // 2048 B
    float* dis  = (float*)(ws + 1050624);       // 2048 B
    float* rs   = (float*)(ws + 1052672);       // 2048 B
    float* Y    = (float*)(ws + 1054720);       // 524,288 B
    float* coef = (float*)(ws + 1579008);       // 1536 B
    u16*   W1   = (u16*)  (ws + 1580544);       // 32,768 B
    u16*   W2   = (u16*)  (ws + 1613312);       // 262,144 B
    u16*   W3   = (u16*)  (ws + 1875456);       // 16,384 B
    float* part = (float*)(ws + 1891840);       // 6,094,848 B

    hipMemsetAsync(S, 0, 1048576 + 2048, stream);    // S + deg
    hipLaunchKernelGGL(deg_k,  dim3(34),  dim3(256), 0, stream, ei, ew, deg);
    hipLaunchKernelGGL(dis_k,  dim3(2),   dim3(256), 0, stream, deg, dis);
    hipLaunchKernelGGL(scat_k, dim3(34),  dim3(256), 0, stream, ei, ew, dis, S);
    hipLaunchKernelGGL(rs_k,   dim3(2),   dim3(256), 0, stream, S, rs);
    hipLaunchKernelGGL(coef_k, dim3(1),   dim3(64),  0, stream,
                       start_w, start_b, filt_w, filt_b, gate_w, gate_b, gcn_w, coef);
    hipLaunchKernelGGL(wconv_k, dim3(512), dim3(256), 0, stream,
                       skip_w, end1_w, end2_w, W1, W2, W3);
    hipLaunchKernelGGL(y_k,    dim3(2, 64), dim3(256), 0, stream, x, S, Y);
    hipLaunchKernelGGL(fused_k, dim3(1984), dim3(256), 0, stream,
                       x, Y, rs, coef, gcn_b, skip_b, end1_b, W1, W2, W3, part);
    hipLaunchKernelGGL(reduce_k, dim3(192), dim3(256), 0, stream, part, end2_b, out);
}